// Round 2
// baseline (815.227 us; speedup 1.0000x reference)
//
#include <hip/hip_runtime.h>

// HellingerDistance: out[n][m] = 0.5*(sum_d a[n] + sum_d b[m]) - sqrt(a[n])·sqrt(b[m])
// N = M = 8192, D = 1024, f32 in/out.
// Strategy: bf16 MFMA GEMM for the cross term (error << 1.39 threshold),
// exact f32 row/col sums fused into the staging loop.

#define NM 8192
#define DD 1024
#define BM 128
#define BN 128
#define BK 64

typedef __attribute__((ext_vector_type(8))) short bf16x8;
typedef __attribute__((ext_vector_type(4))) float f32x4;

// f32 -> bf16 round-to-nearest-even (inputs positive, no NaN/Inf)
static __device__ __forceinline__ unsigned short f2bf(float f) {
  unsigned int u = __float_as_uint(f);
  u += 0x7FFFu + ((u >> 16) & 1u);
  return (unsigned short)(u >> 16);
}

// LDS byte-offset swizzle: linear [row][64] bf16 (128 B/row) would put the
// 16 lanes of a quarter-wave (stride 128 B) all in banks 0-3 (16-way).
// XOR bit pattern (row&7)<<4 spreads them across 8 distinct 16B slots -> 2-way (free).
static __device__ __forceinline__ int swz(int row, int colbytes) {
  return (row * (2 * BK) + colbytes) ^ ((row & 7) << 4);
}

__global__ __launch_bounds__(256, 2)
void hellinger_gemm(const float* __restrict__ A, const float* __restrict__ B,
                    float* __restrict__ C) {
  __shared__ unsigned short As[BM * BK]; // swizzled bf16 sqrt(a) tile
  __shared__ unsigned short Bs[BN * BK]; // swizzled bf16 sqrt(b) tile
  __shared__ float sA[BM];               // rowsum a (exact f32)
  __shared__ float sB[BN];               // rowsum b (exact f32)

  const int t = threadIdx.x;
  const int lane = t & 63;
  const int wave = t >> 6;
  const int wrow = (wave >> 1) * 64; // wave's 64x64 sub-tile
  const int wcol = (wave & 1) * 64;

  const int brow = blockIdx.y * BM;
  const int bcol = blockIdx.x * BN;

  // staging decomposition: thread t handles rows {i*16 + (t>>4)}, cols (t&15)*4..+3
  const int sr = t >> 4;        // 0..15
  const int sc = (t & 15) * 4;  // 0..60 step 4

  const float* ap = A + (size_t)(brow + sr) * DD + sc;
  const float* bp = B + (size_t)(bcol + sr) * DD + sc;

  float racc[8], cacc[8];
#pragma unroll
  for (int i = 0; i < 8; ++i) { racc[i] = 0.f; cacc[i] = 0.f; }

  f32x4 acc[4][4];
#pragma unroll
  for (int m = 0; m < 4; ++m)
#pragma unroll
    for (int n = 0; n < 4; ++n) acc[m][n] = (f32x4){0.f, 0.f, 0.f, 0.f};

  for (int kt = 0; kt < DD / BK; ++kt) {
    // ---- stage A tile (f32 load -> rowsum acc -> sqrt -> bf16 -> LDS) ----
#pragma unroll
    for (int i = 0; i < 8; ++i) {
      const float4 v = *(const float4*)(ap + (size_t)(i * 16) * DD + kt * BK);
      racc[i] += (v.x + v.y) + (v.z + v.w);
      ushort4 p;
      p.x = f2bf(sqrtf(v.x));
      p.y = f2bf(sqrtf(v.y));
      p.z = f2bf(sqrtf(v.z));
      p.w = f2bf(sqrtf(v.w));
      const int row = i * 16 + sr;
      *(ushort4*)((char*)As + swz(row, sc * 2)) = p;
    }
    // ---- stage B tile ----
#pragma unroll
    for (int i = 0; i < 8; ++i) {
      const float4 v = *(const float4*)(bp + (size_t)(i * 16) * DD + kt * BK);
      cacc[i] += (v.x + v.y) + (v.z + v.w);
      ushort4 p;
      p.x = f2bf(sqrtf(v.x));
      p.y = f2bf(sqrtf(v.y));
      p.z = f2bf(sqrtf(v.z));
      p.w = f2bf(sqrtf(v.w));
      const int row = i * 16 + sr;
      *(ushort4*)((char*)Bs + swz(row, sc * 2)) = p;
    }
    __syncthreads();

    // ---- MFMA: 2 K-substeps of 32, 4x4 fragments per wave ----
#pragma unroll
    for (int kk = 0; kk < 2; ++kk) {
      const int koffb = kk * 64 + (lane >> 4) * 16; // byte offset along K
      bf16x8 af[4], bfr[4];
#pragma unroll
      for (int m = 0; m < 4; ++m) {
        const int row = wrow + m * 16 + (lane & 15);
        af[m] = *(const bf16x8*)((const char*)As + swz(row, koffb));
      }
#pragma unroll
      for (int n = 0; n < 4; ++n) {
        const int row = wcol + n * 16 + (lane & 15);
        bfr[n] = *(const bf16x8*)((const char*)Bs + swz(row, koffb));
      }
#pragma unroll
      for (int m = 0; m < 4; ++m)
#pragma unroll
        for (int n = 0; n < 4; ++n)
          acc[m][n] = __builtin_amdgcn_mfma_f32_16x16x32_bf16(af[m], bfr[n], acc[m][n], 0, 0, 0);
    }
    __syncthreads();
  }

  // ---- reduce fused row/col sums: 16 threads (t = 16R+s) share row i*16+R ----
#pragma unroll
  for (int i = 0; i < 8; ++i) {
#pragma unroll
    for (int mask = 1; mask < 16; mask <<= 1) {
      racc[i] += __shfl_xor(racc[i], mask, 64);
      cacc[i] += __shfl_xor(cacc[i], mask, 64);
    }
  }
  if ((t & 15) == 0) {
#pragma unroll
    for (int i = 0; i < 8; ++i) {
      sA[i * 16 + sr] = racc[i];
      sB[i * 16 + sr] = cacc[i];
    }
  }
  __syncthreads();

  // ---- epilogue: C/D layout col=lane&15, row=(lane>>4)*4+j (m89-verified) ----
#pragma unroll
  for (int m = 0; m < 4; ++m) {
    const int rbase = wrow + m * 16 + (lane >> 4) * 4;
#pragma unroll
    for (int j = 0; j < 4; ++j) {
      const int row = rbase + j;
      const float ha = 0.5f * sA[row];
      float* orow = C + (size_t)(brow + row) * NM + bcol;
#pragma unroll
      for (int n = 0; n < 4; ++n) {
        const int col = wcol + n * 16 + (lane & 15);
        orow[col] = ha + 0.5f * sB[col] - acc[m][n][j];
      }
    }
  }
}

extern "C" void kernel_launch(void* const* d_in, const int* in_sizes, int n_in,
                              void* d_out, int out_size, void* d_ws, size_t ws_size,
                              hipStream_t stream) {
  const float* a = (const float*)d_in[0];
  const float* b = (const float*)d_in[1];
  float* out = (float*)d_out;
  dim3 grid(NM / BN, NM / BM);
  hipLaunchKernelGGL(hellinger_gemm, grid, dim3(256), 0, stream, a, b, out);
}

// Round 3
// 239.840 us; speedup vs baseline: 3.3990x; 3.3990x over previous
//
#include <hip/hip_runtime.h>

// HellingerDistance: out[n][m] = 0.5*(rowsum_a[n] + rowsum_b[m]) - sqrt(a[n])·sqrt(b[m])
// N = M = 8192, D = 1024, f32 in/out.
// Round 3: split into (1) preprocess pass -> bf16 sqrt matrices + exact f32 rowsums
// in d_ws, (2) pure bf16 MFMA GEMM (m97 structure: 128^2 tile, BK=64,
// global_load_lds width=16, linear LDS, XCD-bijective swizzle).

#define NM 8192
#define DD 1024

typedef __attribute__((ext_vector_type(8))) short bf16x8;
typedef __attribute__((ext_vector_type(4))) float f32x4;

#define AS1 __attribute__((address_space(1)))
#define AS3 __attribute__((address_space(3)))

// f32 -> bf16 round-to-nearest-even (inputs positive, no NaN/Inf)
static __device__ __forceinline__ unsigned short f2bf(float f) {
  unsigned int u = __float_as_uint(f);
  u += 0x7FFFu + ((u >> 16) & 1u);
  return (unsigned short)(u >> 16);
}

// ---------------- kernel 1: sqrt -> bf16, exact f32 rowsums ----------------
__global__ __launch_bounds__(256)
void hell_prep(const float* __restrict__ A, const float* __restrict__ B,
               unsigned short* __restrict__ SA, unsigned short* __restrict__ SB,
               float* __restrict__ RA, float* __restrict__ RB) {
  __shared__ float wsum[4];
  const int row = blockIdx.x & (NM - 1);
  const bool isB = blockIdx.x >= NM;
  const float* src = (isB ? B : A) + (size_t)row * DD;
  unsigned short* dst = (isB ? SB : SA) + (size_t)row * DD;
  const int t = threadIdx.x;
  const float4 v = ((const float4*)src)[t];
  ushort4 p;
  p.x = f2bf(sqrtf(v.x)); p.y = f2bf(sqrtf(v.y));
  p.z = f2bf(sqrtf(v.z)); p.w = f2bf(sqrtf(v.w));
  ((ushort4*)dst)[t] = p;
  float s = (v.x + v.y) + (v.z + v.w);
#pragma unroll
  for (int m = 1; m < 64; m <<= 1) s += __shfl_xor(s, m, 64);
  if ((t & 63) == 0) wsum[t >> 6] = s;
  __syncthreads();
  if (t == 0) (isB ? RB : RA)[row] = wsum[0] + wsum[1] + wsum[2] + wsum[3];
}

// ---------------- kernel 2: bf16 GEMM + bias epilogue (m97 structure) ------
__global__ __launch_bounds__(256)
void hell_gemm2(const unsigned short* __restrict__ SA,
                const unsigned short* __restrict__ SB,
                const float* __restrict__ RA, const float* __restrict__ RB,
                float* __restrict__ C) {
  __shared__ unsigned short As[128 * 64]; // linear [row][64] bf16
  __shared__ unsigned short Bs[128 * 64];

  const int t = threadIdx.x;
  const int lane = t & 63;
  const int wave = t >> 6;
  const int wrow = (wave >> 1) * 64;
  const int wcol = (wave & 1) * 64;

  // bijective XCD swizzle: nwg = 4096 (64x64 tiles), 8 XCDs, chunk = 512
  const int wg = blockIdx.x;
  const int s = (wg & 7) * 512 + (wg >> 3);
  const int brow = (s >> 6) * 128;
  const int bcol = (s & 63) * 128;

  // staging decomposition: thread t covers row (t>>3) of each 32-row chunk,
  // cols (t&7)*8 .. +7 — matches global_load_lds's lane*16B linear LDS dest.
  const int srow = t >> 3;       // 0..31
  const int scol = (t & 7) * 8;  // 0..56

  f32x4 acc[4][4];
#pragma unroll
  for (int m = 0; m < 4; ++m)
#pragma unroll
    for (int n = 0; n < 4; ++n) acc[m][n] = (f32x4){0.f, 0.f, 0.f, 0.f};

  for (int kt = 0; kt < DD / 64; ++kt) {
#pragma unroll
    for (int i = 0; i < 4; ++i) {
      const unsigned short* ga =
          SA + (size_t)(brow + i * 32 + srow) * DD + kt * 64 + scol;
      __builtin_amdgcn_global_load_lds((const AS1 unsigned int*)ga,
                                       (AS3 unsigned int*)(As + i * 2048 + t * 8),
                                       16, 0, 0);
    }
#pragma unroll
    for (int i = 0; i < 4; ++i) {
      const unsigned short* gb =
          SB + (size_t)(bcol + i * 32 + srow) * DD + kt * 64 + scol;
      __builtin_amdgcn_global_load_lds((const AS1 unsigned int*)gb,
                                       (AS3 unsigned int*)(Bs + i * 2048 + t * 8),
                                       16, 0, 0);
    }
    __syncthreads(); // compiler drains vmcnt before s_barrier

#pragma unroll
    for (int kk = 0; kk < 2; ++kk) {
      const int koff = kk * 32 + (lane >> 4) * 8; // element offset along K
      bf16x8 af[4], bfr[4];
#pragma unroll
      for (int m = 0; m < 4; ++m)
        af[m] = *(const bf16x8*)(As + (wrow + m * 16 + (lane & 15)) * 64 + koff);
#pragma unroll
      for (int n = 0; n < 4; ++n)
        bfr[n] = *(const bf16x8*)(Bs + (wcol + n * 16 + (lane & 15)) * 64 + koff);
#pragma unroll
      for (int m = 0; m < 4; ++m)
#pragma unroll
        for (int n = 0; n < 4; ++n)
          acc[m][n] = __builtin_amdgcn_mfma_f32_16x16x32_bf16(af[m], bfr[n],
                                                              acc[m][n], 0, 0, 0);
    }
    __syncthreads();
  }

  // epilogue: C/D layout col=lane&15, row=(lane>>4)*4+j
#pragma unroll
  for (int m = 0; m < 4; ++m) {
    const int rbase = wrow + m * 16 + (lane >> 4) * 4;
#pragma unroll
    for (int j = 0; j < 4; ++j) {
      const int row = rbase + j;
      const float ha = 0.5f * RA[brow + row];
      float* orow = C + (size_t)(brow + row) * NM + bcol;
#pragma unroll
      for (int n = 0; n < 4; ++n) {
        const int col = wcol + n * 16 + (lane & 15);
        orow[col] = ha + 0.5f * RB[bcol + col] - acc[m][n][j];
      }
    }
  }
}

// ---------------- fallback: round-2 fused kernel (if ws too small) ---------
static __device__ __forceinline__ int swz(int row, int colbytes) {
  return (row * 128 + colbytes) ^ ((row & 7) << 4);
}

__global__ __launch_bounds__(256, 2)
void hellinger_fused(const float* __restrict__ A, const float* __restrict__ B,
                     float* __restrict__ C) {
  __shared__ unsigned short As[128 * 64];
  __shared__ unsigned short Bs[128 * 64];
  __shared__ float sA[128];
  __shared__ float sB[128];

  const int t = threadIdx.x;
  const int lane = t & 63;
  const int wave = t >> 6;
  const int wrow = (wave >> 1) * 64;
  const int wcol = (wave & 1) * 64;
  const int brow = blockIdx.y * 128;
  const int bcol = blockIdx.x * 128;
  const int sr = t >> 4;
  const int sc = (t & 15) * 4;

  const float* ap = A + (size_t)(brow + sr) * DD + sc;
  const float* bp = B + (size_t)(bcol + sr) * DD + sc;

  float racc[8], cacc[8];
#pragma unroll
  for (int i = 0; i < 8; ++i) { racc[i] = 0.f; cacc[i] = 0.f; }

  f32x4 acc[4][4];
#pragma unroll
  for (int m = 0; m < 4; ++m)
#pragma unroll
    for (int n = 0; n < 4; ++n) acc[m][n] = (f32x4){0.f, 0.f, 0.f, 0.f};

  for (int kt = 0; kt < DD / 64; ++kt) {
#pragma unroll
    for (int i = 0; i < 8; ++i) {
      const float4 v = *(const float4*)(ap + (size_t)(i * 16) * DD + kt * 64);
      racc[i] += (v.x + v.y) + (v.z + v.w);
      ushort4 p;
      p.x = f2bf(sqrtf(v.x)); p.y = f2bf(sqrtf(v.y));
      p.z = f2bf(sqrtf(v.z)); p.w = f2bf(sqrtf(v.w));
      *(ushort4*)((char*)As + swz(i * 16 + sr, sc * 2)) = p;
    }
#pragma unroll
    for (int i = 0; i < 8; ++i) {
      const float4 v = *(const float4*)(bp + (size_t)(i * 16) * DD + kt * 64);
      cacc[i] += (v.x + v.y) + (v.z + v.w);
      ushort4 p;
      p.x = f2bf(sqrtf(v.x)); p.y = f2bf(sqrtf(v.y));
      p.z = f2bf(sqrtf(v.z)); p.w = f2bf(sqrtf(v.w));
      *(ushort4*)((char*)Bs + swz(i * 16 + sr, sc * 2)) = p;
    }
    __syncthreads();
#pragma unroll
    for (int kk = 0; kk < 2; ++kk) {
      const int koffb = kk * 64 + (lane >> 4) * 16;
      bf16x8 af[4], bfr[4];
#pragma unroll
      for (int m = 0; m < 4; ++m)
        af[m] = *(const bf16x8*)((const char*)As + swz(wrow + m * 16 + (lane & 15), koffb));
#pragma unroll
      for (int n = 0; n < 4; ++n)
        bfr[n] = *(const bf16x8*)((const char*)Bs + swz(wcol + n * 16 + (lane & 15), koffb));
#pragma unroll
      for (int m = 0; m < 4; ++m)
#pragma unroll
        for (int n = 0; n < 4; ++n)
          acc[m][n] = __builtin_amdgcn_mfma_f32_16x16x32_bf16(af[m], bfr[n], acc[m][n], 0, 0, 0);
    }
    __syncthreads();
  }

#pragma unroll
  for (int i = 0; i < 8; ++i) {
#pragma unroll
    for (int mask = 1; mask < 16; mask <<= 1) {
      racc[i] += __shfl_xor(racc[i], mask, 64);
      cacc[i] += __shfl_xor(cacc[i], mask, 64);
    }
  }
  if ((t & 15) == 0) {
#pragma unroll
    for (int i = 0; i < 8; ++i) { sA[i * 16 + sr] = racc[i]; sB[i * 16 + sr] = cacc[i]; }
  }
  __syncthreads();

#pragma unroll
  for (int m = 0; m < 4; ++m) {
    const int rbase = wrow + m * 16 + (lane >> 4) * 4;
#pragma unroll
    for (int j = 0; j < 4; ++j) {
      const int row = rbase + j;
      const float ha = 0.5f * sA[row];
      float* orow = C + (size_t)(brow + row) * NM + bcol;
#pragma unroll
      for (int n = 0; n < 4; ++n) {
        const int col = wcol + n * 16 + (lane & 15);
        orow[col] = ha + 0.5f * sB[col] - acc[m][n][j];
      }
    }
  }
}

extern "C" void kernel_launch(void* const* d_in, const int* in_sizes, int n_in,
                              void* d_out, int out_size, void* d_ws, size_t ws_size,
                              hipStream_t stream) {
  const float* a = (const float*)d_in[0];
  const float* b = (const float*)d_in[1];
  float* out = (float*)d_out;

  const size_t mat_bytes = (size_t)NM * DD * sizeof(unsigned short); // 16 MB
  const size_t need = 2 * mat_bytes + 2 * (size_t)NM * sizeof(float);

  if (ws_size >= need) {
    unsigned short* SA = (unsigned short*)d_ws;
    unsigned short* SB = (unsigned short*)((char*)d_ws + mat_bytes);
    float* RA = (float*)((char*)d_ws + 2 * mat_bytes);
    float* RB = RA + NM;
    hipLaunchKernelGGL(hell_prep, dim3(2 * NM), dim3(256), 0, stream,
                       a, b, SA, SB, RA, RB);
    hipLaunchKernelGGL(hell_gemm2, dim3(64 * 64), dim3(256), 0, stream,
                       SA, SB, RA, RB, out);
  } else {
    dim3 grid(NM / 128, NM / 128);
    hipLaunchKernelGGL(hellinger_fused, grid, dim3(256), 0, stream, a, b, out);
  }
}

// Round 4
// 176.709 us; speedup vs baseline: 4.6134x; 1.3573x over previous
//
#include <hip/hip_runtime.h>

// HellingerDistance: out[n][m] = 0.5*(rowsum_a[n] + rowsum_b[m]) - sqrt(a[n])·sqrt(b[m])
// N = M = 8192, D = 1024, f32 in/out.
// Round 4: 256x256 tile, BK=64, 8 waves, 2-deep prefetch with counted vmcnt(8),
// both-sides LDS XOR swizzle (linear global_load_lds dest + pre-swizzled global
// source + swizzled ds_read), raw s_barrier + manual waitcnt, setprio on MFMA.

#define NM 8192
#define DD 1024
#define NT 16  // K-tiles of 64

typedef __attribute__((ext_vector_type(8))) short bf16x8;
typedef __attribute__((ext_vector_type(4))) float f32x4;

#define AS1 __attribute__((address_space(1)))
#define AS3 __attribute__((address_space(3)))

#define SCHED0 __builtin_amdgcn_sched_barrier(0)
#define WAIT_LGKM0 do { SCHED0; asm volatile("s_waitcnt lgkmcnt(0)" ::: "memory"); SCHED0; } while (0)
#define WAIT_VM(n)  do { SCHED0; asm volatile("s_waitcnt vmcnt(" #n ")" ::: "memory"); SCHED0; } while (0)

// f32 -> bf16 round-to-nearest-even (inputs positive, no NaN/Inf)
static __device__ __forceinline__ unsigned short f2bf(float f) {
  unsigned int u = __float_as_uint(f);
  u += 0x7FFFu + ((u >> 16) & 1u);
  return (unsigned short)(u >> 16);
}

// ---------------- kernel 1: sqrt -> bf16, exact f32 rowsums ----------------
__global__ __launch_bounds__(256)
void hell_prep(const float* __restrict__ A, const float* __restrict__ B,
               unsigned short* __restrict__ SA, unsigned short* __restrict__ SB,
               float* __restrict__ RA, float* __restrict__ RB) {
  __shared__ float wsum[4];
  const int row = blockIdx.x & (NM - 1);
  const bool isB = blockIdx.x >= NM;
  const float* src = (isB ? B : A) + (size_t)row * DD;
  unsigned short* dst = (isB ? SB : SA) + (size_t)row * DD;
  const int t = threadIdx.x;
  const float4 v = ((const float4*)src)[t];
  ushort4 p;
  p.x = f2bf(sqrtf(v.x)); p.y = f2bf(sqrtf(v.y));
  p.z = f2bf(sqrtf(v.z)); p.w = f2bf(sqrtf(v.w));
  ((ushort4*)dst)[t] = p;
  float s = (v.x + v.y) + (v.z + v.w);
#pragma unroll
  for (int m = 1; m < 64; m <<= 1) s += __shfl_xor(s, m, 64);
  if ((t & 63) == 0) wsum[t >> 6] = s;
  __syncthreads();
  if (t == 0) (isB ? RB : RA)[row] = wsum[0] + wsum[1] + wsum[2] + wsum[3];
}

// ---------------- kernel 2: 256^2 deep-pipelined bf16 GEMM -----------------
// LDS layout per buffer (65536 B): A-tile [256 rows][64 K] bf16 at +0 (32 KB),
// B-tile at +32768. Both-sides swizzle: 16B chunk index within a 128 B row is
// XOR'd with (row&7) — applied to the GLOBAL source (staging) and the ds_read
// address; global_load_lds dest stays linear (rule 21).
__global__ __launch_bounds__(512, 2)
void hell_gemm3(const unsigned short* __restrict__ SA,
                const unsigned short* __restrict__ SB,
                const float* __restrict__ RA, const float* __restrict__ RB,
                float* __restrict__ C) {
  __shared__ __attribute__((aligned(16))) char lds[131072];

  const int t = threadIdx.x;
  const int lane = t & 63;
  const int wave = t >> 6;
  const int wm = wave >> 2;   // 0..1 -> rows wm*128
  const int wn = wave & 3;    // 0..3 -> cols wn*64

  // bijective XCD swizzle: nwg = 1024, 8 XCDs, chunk = 128
  const int wg = blockIdx.x;
  const int s = (wg & 7) * 128 + (wg >> 3);
  const int brow = (s >> 5) * 256;
  const int bcol = (s & 31) * 256;

  // staging: thread t covers LDS row (t>>3) of each 64-row group, chunk t&7.
  // source chunk pre-swizzled so that linear LDS == swizzled content.
  const int sw = ((t >> 3) & 7) ^ (t & 7);
  const unsigned short* ga = SA + (size_t)(brow + (t >> 3)) * DD + sw * 8;
  const unsigned short* gb = SB + (size_t)(bcol + (t >> 3)) * DD + sw * 8;

  const int hi = lane >> 4;   // 0..3
  const int lo = lane & 15;   // fragment row within 16
  const int x7 = lane & 7;    // row&7 for swizzled reads

  f32x4 acc[8][4];
#pragma unroll
  for (int m = 0; m < 8; ++m)
#pragma unroll
    for (int n = 0; n < 4; ++n) acc[m][n] = (f32x4){0.f, 0.f, 0.f, 0.f};

#define STAGE_TILE(KT2, CURB)                                                   \
  do {                                                                          \
    const size_t ko_ = (size_t)(KT2) * 64;                                      \
    _Pragma("unroll")                                                           \
    for (int i_ = 0; i_ < 4; ++i_)                                              \
      __builtin_amdgcn_global_load_lds(                                         \
          (const AS1 unsigned int*)(ga + (size_t)(i_ * 64) * DD + ko_),         \
          (AS3 unsigned int*)(lds + (CURB)*65536 + i_ * 8192 + t * 16), 16, 0, 0); \
    _Pragma("unroll")                                                           \
    for (int i_ = 0; i_ < 4; ++i_)                                              \
      __builtin_amdgcn_global_load_lds(                                         \
          (const AS1 unsigned int*)(gb + (size_t)(i_ * 64) * DD + ko_),         \
          (AS3 unsigned int*)(lds + (CURB)*65536 + 32768 + i_ * 8192 + t * 16), 16, 0, 0); \
  } while (0)

  // prologue: tile0 -> buf0, tile1 -> buf1; wait tile0 (8 of 16 outstanding)
  STAGE_TILE(0, 0);
  STAGE_TILE(1, 1);
  WAIT_VM(8);
  __builtin_amdgcn_s_barrier();

#pragma unroll 1
  for (int kt = 0; kt < NT; ++kt) {
    const int cur = kt & 1;
    const char* Ab = lds + cur * 65536;
    const char* Bb = Ab + 32768;

    // P0: hoist ALL fragments of this tile into registers (swizzled reads).
    bf16x8 af[8][2], bfr[4][2];
#pragma unroll
    for (int m = 0; m < 8; ++m) {
      const int rbyte = wm * 16384 + m * 2048 + lo * 128;
#pragma unroll
      for (int ks = 0; ks < 2; ++ks)
        af[m][ks] = *(const bf16x8*)(Ab + rbyte + (((ks * 4 + hi) ^ x7) << 4));
    }
#pragma unroll
    for (int n = 0; n < 4; ++n) {
      const int rbyte = wn * 8192 + n * 2048 + lo * 128;
#pragma unroll
      for (int ks = 0; ks < 2; ++ks)
        bfr[n][ks] = *(const bf16x8*)(Bb + rbyte + (((ks * 4 + hi) ^ x7) << 4));
    }
    WAIT_LGKM0;                      // reads complete before anyone overwrites
    __builtin_amdgcn_s_barrier();    // all waves done reading buf[cur]

    // P1: stage tile kt+2 into buf[cur] (now safe), then pure MFMA cluster.
    if (kt + 2 < NT) STAGE_TILE(kt + 2, cur);

    __builtin_amdgcn_s_setprio(1);
#pragma unroll
    for (int m = 0; m < 8; ++m)
#pragma unroll
      for (int n = 0; n < 4; ++n)
#pragma unroll
        for (int ks = 0; ks < 2; ++ks)
          acc[m][n] = __builtin_amdgcn_mfma_f32_16x16x32_bf16(af[m][ks], bfr[n][ks],
                                                              acc[m][n], 0, 0, 0);
    __builtin_amdgcn_s_setprio(0);

    // tile end: wait for NEXT tile's 8 loads (counted — kt+2's 8 stay in flight)
    if (kt + 2 < NT) {
      WAIT_VM(8);
      __builtin_amdgcn_s_barrier();
    } else if (kt + 1 < NT) {
      WAIT_VM(0);
      __builtin_amdgcn_s_barrier();
    }
  }
#undef STAGE_TILE

  // epilogue: C/D layout col=lane&15, row=(lane>>4)*4+j
  float hrb[4];
#pragma unroll
  for (int n = 0; n < 4; ++n)
    hrb[n] = 0.5f * RB[bcol + wn * 64 + n * 16 + lo];
#pragma unroll
  for (int m = 0; m < 8; ++m) {
    const int rbase = wm * 128 + m * 16 + hi * 4;
#pragma unroll
    for (int j = 0; j < 4; ++j) {
      const int row = rbase + j;
      const float ha = 0.5f * RA[brow + row];
      float* orow = C + (size_t)(brow + row) * NM + bcol;
#pragma unroll
      for (int n = 0; n < 4; ++n)
        orow[wn * 64 + n * 16 + lo] = ha + hrb[n] - acc[m][n][j];
    }
  }
}

// ---------------- fallback: fused kernel (if ws too small) -----------------
static __device__ __forceinline__ int swz(int row, int colbytes) {
  return (row * 128 + colbytes) ^ ((row & 7) << 4);
}

__global__ __launch_bounds__(256, 2)
void hellinger_fused(const float* __restrict__ A, const float* __restrict__ B,
                     float* __restrict__ C) {
  __shared__ unsigned short As[128 * 64];
  __shared__ unsigned short Bs[128 * 64];
  __shared__ float sA[128];
  __shared__ float sB[128];

  const int t = threadIdx.x;
  const int lane = t & 63;
  const int wave = t >> 6;
  const int wrow = (wave >> 1) * 64;
  const int wcol = (wave & 1) * 64;
  const int brow = blockIdx.y * 128;
  const int bcol = blockIdx.x * 128;
  const int sr = t >> 4;
  const int sc = (t & 15) * 4;

  const float* ap = A + (size_t)(brow + sr) * DD + sc;
  const float* bp = B + (size_t)(bcol + sr) * DD + sc;

  float racc[8], cacc[8];
#pragma unroll
  for (int i = 0; i < 8; ++i) { racc[i] = 0.f; cacc[i] = 0.f; }

  f32x4 acc[4][4];
#pragma unroll
  for (int m = 0; m < 4; ++m)
#pragma unroll
    for (int n = 0; n < 4; ++n) acc[m][n] = (f32x4){0.f, 0.f, 0.f, 0.f};

  for (int kt = 0; kt < DD / 64; ++kt) {
#pragma unroll
    for (int i = 0; i < 8; ++i) {
      const float4 v = *(const float4*)(ap + (size_t)(i * 16) * DD + kt * 64);
      racc[i] += (v.x + v.y) + (v.z + v.w);
      ushort4 p;
      p.x = f2bf(sqrtf(v.x)); p.y = f2bf(sqrtf(v.y));
      p.z = f2bf(sqrtf(v.z)); p.w = f2bf(sqrtf(v.w));
      *(ushort4*)((char*)As + swz(i * 16 + sr, sc * 2)) = p;
    }
#pragma unroll
    for (int i = 0; i < 8; ++i) {
      const float4 v = *(const float4*)(bp + (size_t)(i * 16) * DD + kt * 64);
      cacc[i] += (v.x + v.y) + (v.z + v.w);
      ushort4 p;
      p.x = f2bf(sqrtf(v.x)); p.y = f2bf(sqrtf(v.y));
      p.z = f2bf(sqrtf(v.z)); p.w = f2bf(sqrtf(v.w));
      *(ushort4*)((char*)Bs + swz(i * 16 + sr, sc * 2)) = p;
    }
    __syncthreads();
#pragma unroll
    for (int kk = 0; kk < 2; ++kk) {
      const int koffb = kk * 64 + (lane >> 4) * 16;
      bf16x8 af[4], bfr[4];
#pragma unroll
      for (int m = 0; m < 4; ++m)
        af[m] = *(const bf16x8*)((const char*)As + swz(wrow + m * 16 + (lane & 15), koffb));
#pragma unroll
      for (int n = 0; n < 4; ++n)
        bfr[n] = *(const bf16x8*)((const char*)Bs + swz(wcol + n * 16 + (lane & 15), koffb));
#pragma unroll
      for (int m = 0; m < 4; ++m)
#pragma unroll
        for (int n = 0; n < 4; ++n)
          acc[m][n] = __builtin_amdgcn_mfma_f32_16x16x32_bf16(af[m], bfr[n], acc[m][n], 0, 0, 0);
    }
    __syncthreads();
  }

#pragma unroll
  for (int i = 0; i < 8; ++i) {
#pragma unroll
    for (int mask = 1; mask < 16; mask <<= 1) {
      racc[i] += __shfl_xor(racc[i], mask, 64);
      cacc[i] += __shfl_xor(cacc[i], mask, 64);
    }
  }
  if ((t & 15) == 0) {
#pragma unroll
    for (int i = 0; i < 8; ++i) { sA[i * 16 + sr] = racc[i]; sB[i * 16 + sr] = cacc[i]; }
  }
  __syncthreads();

#pragma unroll
  for (int m = 0; m < 4; ++m) {
    const int rbase = wrow + m * 16 + (lane >> 4) * 4;
#pragma unroll
    for (int j = 0; j < 4; ++j) {
      const int row = rbase + j;
      const float ha = 0.5f * sA[row];
      float* orow = C + (size_t)(brow + row) * NM + bcol;
#pragma unroll
      for (int n = 0; n < 4; ++n) {
        const int col = wcol + n * 16 + (lane & 15);
        orow[col] = ha + 0.5f * sB[col] - acc[m][n][j];
      }
    }
  }
}

extern "C" void kernel_launch(void* const* d_in, const int* in_sizes, int n_in,
                              void* d_out, int out_size, void* d_ws, size_t ws_size,
                              hipStream_t stream) {
  const float* a = (const float*)d_in[0];
  const float* b = (const float*)d_in[1];
  float* out = (float*)d_out;

  const size_t mat_bytes = (size_t)NM * DD * sizeof(unsigned short); // 16 MB
  const size_t need = 2 * mat_bytes + 2 * (size_t)NM * sizeof(float);

  if (ws_size >= need) {
    unsigned short* SA = (unsigned short*)d_ws;
    unsigned short* SB = (unsigned short*)((char*)d_ws + mat_bytes);
    float* RA = (float*)((char*)d_ws + 2 * mat_bytes);
    float* RB = RA + NM;
    hipLaunchKernelGGL(hell_prep, dim3(2 * NM), dim3(256), 0, stream,
                       a, b, SA, SB, RA, RB);
    hipLaunchKernelGGL(hell_gemm3, dim3(32 * 32), dim3(512), 0, stream,
                       SA, SB, RA, RB, out);
  } else {
    dim3 grid(NM / 128, NM / 128);
    hipLaunchKernelGGL(hellinger_fused, grid, dim3(256), 0, stream, a, b, out);
  }
}